// Round 1
// baseline (335.584 us; speedup 1.0000x reference)
//
#include <hip/hip_runtime.h>
#include <math.h>

#define BATCH 4
#define IMG 64
#define NSAMP 24
#define HID 128
#define LATN 128
#define PIX 4
#define MPT (PIX*NSAMP)   /* 96 points per block */
#define FOV_T 0.57735026918962576f
#define CAMD 2.0f
#define NEARP 1.0f
#define STEP (2.0f/24.0f)
#define SHARP 50.0f

/* workspace layout (floats) */
#define WS_LAT1 0                 /* B*128 */
#define WS_CAMR (BATCH*HID)       /* B*12  */
#define WS_W2T  1024              /* 128*128 */

__global__ void setup_batch(const float* __restrict__ latents,
                            const float* __restrict__ phis,
                            const float* __restrict__ thetas,
                            const float* __restrict__ w1,
                            const float* __restrict__ b1,
                            float* __restrict__ ws) {
    int b = blockIdx.x, j = threadIdx.x;
    float acc = b1[j];
    for (int k = 0; k < LATN; ++k)
        acc = fmaf(latents[b*LATN + k], w1[(3+k)*HID + j], acc);
    ws[WS_LAT1 + b*HID + j] = acc;
    if (j == 0) {
        float ph = phis[b], th = thetas[b];
        float cp = cosf(ph), sp = sinf(ph), ct = cosf(th), st = sinf(th);
        float cx = CAMD*cp*st, cy = CAMD*sp, cz = CAMD*cp*ct;
        float nc = sqrtf(cx*cx + cy*cy + cz*cz);
        float fx = -cx/nc, fy = -cy/nc, fz = -cz/nc;
        /* right = normalize(cross((0,1,0), f)) = (fz, 0, -fx)/|.| */
        float rx = fz, ry = 0.0f, rz = -fx;
        float nr = sqrtf(rx*rx + rz*rz);
        rx /= nr; rz /= nr;
        /* up = cross(f, right) */
        float ux = fy*rz - fz*ry;
        float uy = fz*rx - fx*rz;
        float uz = fx*ry - fy*rx;
        float* c = ws + WS_CAMR + b*12;
        c[0]=cx; c[1]=cy; c[2]=cz;
        c[3]=rx; c[4]=ry; c[5]=rz;
        c[6]=ux; c[7]=uy; c[8]=uz;
        c[9]=fx; c[10]=fy; c[11]=fz;
    }
}

__global__ void setup_w2t(const float* __restrict__ w2, float* __restrict__ ws) {
    int j = blockIdx.x, k = threadIdx.x;
    ws[WS_W2T + j*HID + k] = w2[k*HID + j];
}

__device__ __forceinline__ float blockReduce(float v, float* red, int t) {
    #pragma unroll
    for (int off = 32; off > 0; off >>= 1) v += __shfl_xor(v, off, 64);
    __syncthreads();                       /* guard red reuse */
    if ((t & 63) == 0) red[t >> 6] = v;
    __syncthreads();
    return red[0] + red[1] + red[2] + red[3];
}

#define FMA4(a, hc, wv) \
    a.x = fmaf(hc, wv.x, a.x); a.y = fmaf(hc, wv.y, a.y); \
    a.z = fmaf(hc, wv.z, a.z); a.w = fmaf(hc, wv.w, a.w);

__global__ __launch_bounds__(256)
void render_kernel(const float* __restrict__ samples_u,
                   const float* __restrict__ w1,
                   const float* __restrict__ w2,
                   const float* __restrict__ b2,
                   const float* __restrict__ w_sdf,
                   const float* __restrict__ b_sdf,
                   const float* __restrict__ w_tex,
                   const float* __restrict__ b_tex,
                   const float* __restrict__ ws,
                   float* __restrict__ out) {
    __shared__ __align__(16) float h1s[MPT*HID];   /* 48 KB */
    __shared__ float Ps[MPT][3];
    __shared__ float vals[MPT];
    __shared__ float camR[12];
    __shared__ int   hitMs[PIX];
    __shared__ int   maskq[PIX];
    __shared__ float red[4];
    __shared__ float h1p[HID];
    __shared__ float dz2p[HID];

    const int t    = threadIdx.x;
    const int blk  = blockIdx.x;
    const int b    = blk >> 10;
    const int tile = blk & 1023;

    if (t < 12) camR[t] = ws[WS_CAMR + b*12 + t];
    if (t < PIX) {
        int p = tile*PIX + t;
        int x = p & 63, y = p >> 6;
        float xx = ((x + 0.5f)*(2.0f/IMG) - 1.0f)*FOV_T;
        float yy = ((y + 0.5f)*(2.0f/IMG) - 1.0f)*FOV_T;
        float n2 = xx*xx + yy*yy + 1.0f;
        maskq[t] = (4.0f - 3.0f*n2) >= 0.0f ? 1 : 0;   /* disc = 4/n2-3 >= 0 */
    }
    __syncthreads();

    /* fully-unmasked tile: write zeros, done */
    if (!(maskq[0] | maskq[1] | maskq[2] | maskq[3])) {
        if (t < 12) {
            int q = t & 3, ch = t >> 2;
            int p = tile*PIX + q;
            int x = p & 63, y = p >> 6;
            out[((b*3 + ch)*IMG + y)*IMG + x] = 0.0f;
        }
        return;
    }

    /* sample points */
    if (t < MPT) {
        int q = t / NSAMP, s = t - q*NSAMP;
        int p = tile*PIX + q;
        int x = p & 63, y = p >> 6;
        float xx =  ((x + 0.5f)*(2.0f/IMG) - 1.0f)*FOV_T;
        float yy = -(((y + 0.5f)*(2.0f/IMG) - 1.0f)*FOV_T);
        float inv = 1.0f/sqrtf(xx*xx + yy*yy + 1.0f);
        float d0 = xx*inv, d1 = yy*inv, d2 = -inv;
        float rxv = camR[3]*d0 + camR[6]*d1 - camR[9]*d2;
        float ryv = camR[4]*d0 + camR[7]*d1 - camR[10]*d2;
        float rzv = camR[5]*d0 + camR[8]*d1 - camR[11]*d2;
        float u  = samples_u[(y*IMG + x)*NSAMP + s];
        float tv = (s + u)*STEP + NEARP;
        Ps[t][0] = fmaf(rxv, tv, camR[0]);
        Ps[t][1] = fmaf(ryv, tv, camR[1]);
        Ps[t][2] = fmaf(rzv, tv, camR[2]);
    }
    __syncthreads();

    /* layer 1: h1[m][j] = relu(P[m].w1c[:,j] + lat1[j]) */
    {
        int j = t & 127, half = t >> 7;
        float latv = ws[WS_LAT1 + b*HID + j];
        float w10 = w1[j], w11 = w1[HID + j], w12 = w1[2*HID + j];
        #pragma unroll
        for (int mi = 0; mi < MPT/2; ++mi) {
            int m = mi*2 + half;
            float z = fmaf(Ps[m][0], w10, fmaf(Ps[m][1], w11, fmaf(Ps[m][2], w12, latv)));
            h1s[m*HID + j] = fmaxf(z, 0.0f);
        }
    }
    __syncthreads();

    /* layer 2 + sdf: val[m] = relu(h1[m]@w2 + b2) . w_sdf + b_sdf */
    {
        int jg = t & 31, mg = t >> 5;     /* 8 m-groups x 12 m, 32 j-groups x 4 j */
        int j0 = jg*4;
        const float4* w2v = (const float4*)w2;
        float4 acc[12];
        float4 bb = *(const float4*)&b2[j0];
        #pragma unroll
        for (int mi = 0; mi < 12; ++mi) acc[mi] = bb;
        for (int k = 0; k < HID; k += 4) {
            float4 wa = w2v[(k+0)*32 + jg];
            float4 wb = w2v[(k+1)*32 + jg];
            float4 wc = w2v[(k+2)*32 + jg];
            float4 wd = w2v[(k+3)*32 + jg];
            #pragma unroll
            for (int mi = 0; mi < 12; ++mi) {
                const float4 h = *(const float4*)&h1s[(mg*12 + mi)*HID + k];
                float4 a = acc[mi];
                FMA4(a, h.x, wa); FMA4(a, h.y, wb);
                FMA4(a, h.z, wc); FMA4(a, h.w, wd);
                acc[mi] = a;
            }
        }
        float4 wsd = *(const float4*)&w_sdf[j0];
        float bsd = b_sdf[0];
        #pragma unroll
        for (int mi = 0; mi < 12; ++mi) {
            float4 a = acc[mi];
            float c = fmaxf(a.x,0.0f)*wsd.x + fmaxf(a.y,0.0f)*wsd.y
                    + fmaxf(a.z,0.0f)*wsd.z + fmaxf(a.w,0.0f)*wsd.w;
            #pragma unroll
            for (int off = 16; off > 0; off >>= 1) c += __shfl_xor(c, off, 32);
            if (jg == 0) vals[mg*12 + mi] = c + bsd;
        }
    }
    __syncthreads();

    /* hit selection: first s with val<=0, else argmin (first-min) */
    if (t < PIX) {
        int base = t*NSAMP;
        int idx = -1, bidx = 0;
        float bestv = 3.0e38f;
        for (int s = 0; s < NSAMP; ++s) {
            float v = vals[base + s];
            if (idx < 0 && v <= 0.0f) idx = s;
            if (v < bestv) { bestv = v; bidx = s; }
        }
        hitMs[t] = base + (idx >= 0 ? idx : bidx);
    }
    __syncthreads();

    /* shading: forward + texture + backward(normal) per hit point */
    const float* w2t = ws + WS_W2T;
    for (int pt = 0; pt < PIX; ++pt) {
        int hm = hitMs[pt];
        float hx = Ps[hm][0], hy = Ps[hm][1], hz = Ps[hm][2];
        float h1v = 0.0f;
        if (t < HID) {
            float z = fmaf(hx, w1[t], fmaf(hy, w1[HID+t], fmaf(hz, w1[2*HID+t],
                          ws[WS_LAT1 + b*HID + t])));
            h1v = fmaxf(z, 0.0f);
            h1p[t] = h1v;
        }
        __syncthreads();
        float h2v = 0.0f;
        if (t < HID) {
            float a = b2[t];
            for (int k = 0; k < HID; ++k) a = fmaf(h1p[k], w2[k*HID + t], a);
            h2v = fmaxf(a, 0.0f);
            dz2p[t] = (a > 0.0f) ? w_sdf[t] : 0.0f;
        }
        __syncthreads();
        float val  = blockReduce((t < HID) ? h2v*w_sdf[t]     : 0.0f, red, t) + b_sdf[0];
        float tex0 = blockReduce((t < HID) ? h2v*w_tex[t*3+0] : 0.0f, red, t) + b_tex[0];
        float tex1 = blockReduce((t < HID) ? h2v*w_tex[t*3+1] : 0.0f, red, t) + b_tex[1];
        float tex2 = blockReduce((t < HID) ? h2v*w_tex[t*3+2] : 0.0f, red, t) + b_tex[2];
        float dp0 = 0.0f, dp1 = 0.0f, dp2 = 0.0f;
        if (t < HID) {
            float dh1 = 0.0f;
            for (int j = 0; j < HID; ++j) dh1 = fmaf(w2t[j*HID + t], dz2p[j], dh1);
            float dz1 = (h1v > 0.0f) ? dh1 : 0.0f;
            dp0 = w1[t]*dz1; dp1 = w1[HID+t]*dz1; dp2 = w1[2*HID+t]*dz1;
        }
        float g0 = blockReduce(dp0, red, t);
        float g1 = blockReduce(dp1, red, t);
        float g2 = blockReduce(dp2, red, t);
        if (t == 0) {
            float nn = sqrtf(g0*g0 + g1*g1 + g2*g2) + 1e-8f;
            const float is3 = 0.57735026918962576f;   /* 1/sqrt(3) */
            float lam = (g0 + g1 + g2)*is3/nn;
            lam = fminf(fmaxf(lam, 0.0f), 1.0f);
            float hw = 1.0f/(1.0f + expf(val*SHARP));  /* sigmoid(-val*50) */
            float sh = (0.2f + 0.8f*lam)*hw;
            int p = tile*PIX + pt;
            int x = p & 63, y = p >> 6;
            float o0 = 0.0f, o1 = 0.0f, o2 = 0.0f;
            if (maskq[pt]) {
                o0 = sh/(1.0f + expf(-tex0));
                o1 = sh/(1.0f + expf(-tex1));
                o2 = sh/(1.0f + expf(-tex2));
            }
            out[((b*3 + 0)*IMG + y)*IMG + x] = o0;
            out[((b*3 + 1)*IMG + y)*IMG + x] = o1;
            out[((b*3 + 2)*IMG + y)*IMG + x] = o2;
        }
        __syncthreads();
    }
}

extern "C" void kernel_launch(void* const* d_in, const int* in_sizes, int n_in,
                              void* d_out, int out_size, void* d_ws, size_t ws_size,
                              hipStream_t stream) {
    const float* latents   = (const float*)d_in[0];
    const float* phis      = (const float*)d_in[1];
    const float* thetas    = (const float*)d_in[2];
    const float* samples_u = (const float*)d_in[3];
    const float* w1        = (const float*)d_in[4];
    const float* b1        = (const float*)d_in[5];
    const float* w2        = (const float*)d_in[6];
    const float* b2        = (const float*)d_in[7];
    const float* w_sdf     = (const float*)d_in[8];
    const float* b_sdf     = (const float*)d_in[9];
    const float* w_tex     = (const float*)d_in[10];
    const float* b_tex     = (const float*)d_in[11];
    float* out = (float*)d_out;
    float* ws  = (float*)d_ws;

    setup_batch<<<dim3(BATCH), dim3(HID), 0, stream>>>(latents, phis, thetas, w1, b1, ws);
    setup_w2t<<<dim3(HID), dim3(HID), 0, stream>>>(w2, ws);
    render_kernel<<<dim3(BATCH*(IMG*IMG/PIX)), dim3(256), 0, stream>>>(
        samples_u, w1, w2, b2, w_sdf, b_sdf, w_tex, b_tex, ws, out);
}

// Round 4
// 270.571 us; speedup vs baseline: 1.2403x; 1.2403x over previous
//
#include <hip/hip_runtime.h>
#include <math.h>

#define BATCH 4
#define IMG 64
#define NSAMP 24
#define HID 128
#define LATN 128
#define PIX 8
#define MPT (PIX*NSAMP)   /* 192 points per block */
#define CHUNK 64
#define NCHUNK 3
#define PADH 132          /* 132 % 32 == 4 -> baseline conflict-free b128 */
#define FOV_T 0.57735026918962576f
#define CAMD 2.0f
#define NEARP 1.0f
#define STEP (2.0f/24.0f)
#define SHARP 50.0f

/* workspace layout (floats) */
#define WS_LAT1 0                 /* B*128 */
#define WS_CAMR (BATCH*HID)       /* B*12  */
#define WS_W2T  1024              /* 128*128 */

__global__ void setup_batch(const float* __restrict__ latents,
                            const float* __restrict__ phis,
                            const float* __restrict__ thetas,
                            const float* __restrict__ w1,
                            const float* __restrict__ b1,
                            float* __restrict__ ws) {
    int b = blockIdx.x, j = threadIdx.x;
    float acc = b1[j];
    for (int k = 0; k < LATN; ++k)
        acc = fmaf(latents[b*LATN + k], w1[(3+k)*HID + j], acc);
    ws[WS_LAT1 + b*HID + j] = acc;
    if (j == 0) {
        float ph = phis[b], th = thetas[b];
        float cp = cosf(ph), sp = sinf(ph), ct = cosf(th), st = sinf(th);
        float cx = CAMD*cp*st, cy = CAMD*sp, cz = CAMD*cp*ct;
        float nc = sqrtf(cx*cx + cy*cy + cz*cz);
        float fx = -cx/nc, fy = -cy/nc, fz = -cz/nc;
        float rx = fz, rz = -fx;
        float nr = sqrtf(rx*rx + rz*rz);
        rx /= nr; rz /= nr;
        float ux = fy*rz;
        float uy = fz*rx - fx*rz;
        float uz = -fy*rx;
        float* c = ws + WS_CAMR + b*12;
        c[0]=cx; c[1]=cy; c[2]=cz;
        c[3]=rx; c[4]=0.0f; c[5]=rz;
        c[6]=ux; c[7]=uy; c[8]=uz;
        c[9]=fx; c[10]=fy; c[11]=fz;
    }
}

__global__ void setup_w2t(const float* __restrict__ w2, float* __restrict__ ws) {
    int j = blockIdx.x, k = threadIdx.x;
    ws[WS_W2T + j*HID + k] = w2[k*HID + j];
}

__global__ __launch_bounds__(256)
void render_kernel(const float* __restrict__ samples_u,
                   const float* __restrict__ w1,
                   const float* __restrict__ w2,
                   const float* __restrict__ b2,
                   const float* __restrict__ w_sdf,
                   const float* __restrict__ b_sdf,
                   const float* __restrict__ w_tex,
                   const float* __restrict__ b_tex,
                   const float* __restrict__ ws,
                   float* __restrict__ out) {
    __shared__ __align__(16) float h1s[CHUNK*PADH];  /* 33 KB, reused per chunk */
    __shared__ float Ps[MPT][3];
    __shared__ float vals[MPT];
    __shared__ float vpart[256];
    __shared__ float lat1s[HID];
    __shared__ float camR[12];
    __shared__ int   hitMs[PIX];
    __shared__ int   maskq[PIX];

    const int t    = threadIdx.x;
    const int lane = t & 63;
    const int wv   = __builtin_amdgcn_readfirstlane(t >> 6);  /* wave id 0..3 */
    const int blk  = blockIdx.x;
    const int b    = blk >> 9;
    const int tile = blk & 511;

    if (t < 12)  camR[t]  = ws[WS_CAMR + b*12 + t];
    if (t < HID) lat1s[t] = ws[WS_LAT1 + b*HID + t];
    if (t < PIX) {
        int p = tile*PIX + t;
        int x = p & 63, y = p >> 6;
        float xx = ((x + 0.5f)*(2.0f/IMG) - 1.0f)*FOV_T;
        float yy = ((y + 0.5f)*(2.0f/IMG) - 1.0f)*FOV_T;
        float n2 = xx*xx + yy*yy + 1.0f;
        maskq[t] = (4.0f - 3.0f*n2) >= 0.0f ? 1 : 0;
    }
    __syncthreads();

    /* fully-unmasked tile: write zeros, done */
    {
        int any = maskq[0]|maskq[1]|maskq[2]|maskq[3]|maskq[4]|maskq[5]|maskq[6]|maskq[7];
        if (!any) {
            if (t < PIX*3) {
                int q = t & 7, ch = t >> 3;
                int p = tile*PIX + q;
                int x = p & 63, y = p >> 6;
                out[((b*3 + ch)*IMG + y)*IMG + x] = 0.0f;
            }
            return;
        }
    }

    /* sample points for all 192 m */
    if (t < MPT) {
        int q = t / NSAMP, s = t - q*NSAMP;
        int p = tile*PIX + q;
        int x = p & 63, y = p >> 6;
        float xx =  ((x + 0.5f)*(2.0f/IMG) - 1.0f)*FOV_T;
        float yy = -(((y + 0.5f)*(2.0f/IMG) - 1.0f)*FOV_T);
        float inv = 1.0f/sqrtf(xx*xx + yy*yy + 1.0f);
        float d0 = xx*inv, d1 = yy*inv, d2 = -inv;
        float rxv = camR[3]*d0 + camR[6]*d1 - camR[9]*d2;
        float ryv = camR[4]*d0 + camR[7]*d1 - camR[10]*d2;
        float rzv = camR[5]*d0 + camR[8]*d1 - camR[11]*d2;
        float u  = samples_u[(y*IMG + x)*NSAMP + s];
        float tv = (s + u)*STEP + NEARP;
        Ps[t][0] = fmaf(rxv, tv, camR[0]);
        Ps[t][1] = fmaf(ryv, tv, camR[1]);
        Ps[t][2] = fmaf(rzv, tv, camR[2]);
    }
    __syncthreads();

    /* ---- march: 3 chunks of 64 points ---- */
    {
        const int j = t & 127, half = t >> 7;
        const float w10 = w1[j], w11 = w1[HID + j], w12 = w1[2*HID + j];
        const float latv = lat1s[j];
        const float* wp  = w2 + wv*32;       /* wave-uniform column slice */
        const float* b2p = b2 + wv*32;
        const float* wsd = w_sdf + wv*32;

        for (int c = 0; c < NCHUNK; ++c) {
            const int c0 = c*CHUNK;
            /* layer 1: h1[ml][j] for ml in [0,64) */
            #pragma unroll 4
            for (int i = 0; i < CHUNK/2; ++i) {
                int ml = half*(CHUNK/2) + i;
                float z = fmaf(Ps[c0+ml][0], w10,
                          fmaf(Ps[c0+ml][1], w11,
                          fmaf(Ps[c0+ml][2], w12, latv)));
                h1s[ml*PADH + j] = fmaxf(z, 0.0f);
            }
            __syncthreads();

            /* layer 2: lane = point, wave = 32-j slice, w2 via scalar path */
            float acc[32];
            #pragma unroll
            for (int jj = 0; jj < 32; ++jj) acc[jj] = 0.0f;
            const float4* hrow = (const float4*)&h1s[lane*PADH];
            for (int k = 0; k < HID; k += 4) {
                float4 h = hrow[k >> 2];
                #pragma unroll
                for (int kk = 0; kk < 4; ++kk) {
                    float hk = (&h.x)[kk];
                    const float* wr = wp + (k + kk)*HID;
                    #pragma unroll
                    for (int jj = 0; jj < 32; ++jj)
                        acc[jj] = fmaf(hk, wr[jj], acc[jj]);
                }
            }
            float val = 0.0f;
            #pragma unroll
            for (int jj = 0; jj < 32; ++jj)
                val += fmaxf(acc[jj] + b2p[jj], 0.0f) * wsd[jj];
            vpart[t] = val;
            __syncthreads();
            if (t < CHUNK)
                vals[c0 + t] = vpart[t] + vpart[64 + t] + vpart[128 + t]
                             + vpart[192 + t] + b_sdf[0];
            /* next layer1 write is fenced by the barrier at loop top / below */
            __syncthreads();
        }
    }

    /* hit selection */
    if (t < PIX) {
        int base = t*NSAMP;
        int idx = -1, bidx = 0;
        float bestv = 3.0e38f;
        for (int s = 0; s < NSAMP; ++s) {
            float v = vals[base + s];
            if (idx < 0 && v <= 0.0f) idx = s;
            if (v < bestv) { bestv = v; bidx = s; }
        }
        hitMs[t] = base + (idx >= 0 ? idx : bidx);
    }
    __syncthreads();

    /* ---- shading: one pixel per wave, 2 passes; wave-private LDS ---- */
    float* h1p  = h1s;            /* [4][128] overlay */
    float* dz2p = h1s + 4*HID;    /* [4][128] overlay */
    const float* w2t = ws + WS_W2T;
    const int j0 = lane, j1 = lane + 64;

    for (int pp = 0; pp < 2; ++pp) {
        int pt = pp*4 + wv;
        int hm = hitMs[pt];
        float hx = Ps[hm][0], hy = Ps[hm][1], hz = Ps[hm][2];

        float z0 = fmaf(hx, w1[j0], fmaf(hy, w1[HID+j0], fmaf(hz, w1[2*HID+j0], lat1s[j0])));
        float z1 = fmaf(hx, w1[j1], fmaf(hy, w1[HID+j1], fmaf(hz, w1[2*HID+j1], lat1s[j1])));
        float h10 = fmaxf(z0, 0.0f), h11 = fmaxf(z1, 0.0f);
        h1p[wv*HID + j0] = h10;
        h1p[wv*HID + j1] = h11;   /* intra-wave DS ordering suffices */

        /* forward h2 for j0,j1 with 4-way accumulators */
        float a00=0,a01=0,a02=0,a03=0, a10=0,a11=0,a12=0,a13=0;
        for (int k = 0; k < HID; k += 4) {
            float4 hv = *(const float4*)&h1p[wv*HID + k];
            a00 = fmaf(hv.x, w2[(k+0)*HID + j0], a00);
            a10 = fmaf(hv.x, w2[(k+0)*HID + j1], a10);
            a01 = fmaf(hv.y, w2[(k+1)*HID + j0], a01);
            a11 = fmaf(hv.y, w2[(k+1)*HID + j1], a11);
            a02 = fmaf(hv.z, w2[(k+2)*HID + j0], a02);
            a12 = fmaf(hv.z, w2[(k+2)*HID + j1], a12);
            a03 = fmaf(hv.w, w2[(k+3)*HID + j0], a03);
            a13 = fmaf(hv.w, w2[(k+3)*HID + j1], a13);
        }
        float za = (a00+a01)+(a02+a03) + b2[j0];
        float zb = (a10+a11)+(a12+a13) + b2[j1];
        float h20 = fmaxf(za, 0.0f), h21 = fmaxf(zb, 0.0f);
        float wsd0 = w_sdf[j0], wsd1 = w_sdf[j1];
        dz2p[wv*HID + j0] = (za > 0.0f) ? wsd0 : 0.0f;
        dz2p[wv*HID + j1] = (zb > 0.0f) ? wsd1 : 0.0f;

        float pv = h20*wsd0 + h21*wsd1;
        float p0 = h20*w_tex[j0*3+0] + h21*w_tex[j1*3+0];
        float p1 = h20*w_tex[j0*3+1] + h21*w_tex[j1*3+1];
        float p2 = h20*w_tex[j0*3+2] + h21*w_tex[j1*3+2];
        #pragma unroll
        for (int off = 32; off > 0; off >>= 1) {
            pv += __shfl_xor(pv, off, 64);
            p0 += __shfl_xor(p0, off, 64);
            p1 += __shfl_xor(p1, off, 64);
            p2 += __shfl_xor(p2, off, 64);
        }

        /* backward: dh1 = w2t . dz2 */
        float d00=0,d01=0,d02=0,d03=0, d10=0,d11=0,d12=0,d13=0;
        for (int k = 0; k < HID; k += 4) {
            float4 dv = *(const float4*)&dz2p[wv*HID + k];
            d00 = fmaf(dv.x, w2t[(k+0)*HID + j0], d00);
            d10 = fmaf(dv.x, w2t[(k+0)*HID + j1], d10);
            d01 = fmaf(dv.y, w2t[(k+1)*HID + j0], d01);
            d11 = fmaf(dv.y, w2t[(k+1)*HID + j1], d11);
            d02 = fmaf(dv.z, w2t[(k+2)*HID + j0], d02);
            d12 = fmaf(dv.z, w2t[(k+2)*HID + j1], d12);
            d03 = fmaf(dv.w, w2t[(k+3)*HID + j0], d03);
            d13 = fmaf(dv.w, w2t[(k+3)*HID + j1], d13);
        }
        float dh0 = (d00+d01)+(d02+d03);
        float dh1v = (d10+d11)+(d12+d13);
        float dz10 = (h10 > 0.0f) ? dh0 : 0.0f;
        float dz11 = (h11 > 0.0f) ? dh1v : 0.0f;
        float g0 = w1[j0]*dz10 + w1[j1]*dz11;
        float g1 = w1[HID+j0]*dz10 + w1[HID+j1]*dz11;
        float g2 = w1[2*HID+j0]*dz10 + w1[2*HID+j1]*dz11;
        #pragma unroll
        for (int off = 32; off > 0; off >>= 1) {
            g0 += __shfl_xor(g0, off, 64);
            g1 += __shfl_xor(g1, off, 64);
            g2 += __shfl_xor(g2, off, 64);
        }

        if (lane == 0) {
            float val = pv + b_sdf[0];
            float nn = sqrtf(g0*g0 + g1*g1 + g2*g2) + 1e-8f;
            const float is3 = 0.57735026918962576f;
            float lam = (g0 + g1 + g2)*is3/nn;
            lam = fminf(fmaxf(lam, 0.0f), 1.0f);
            float hw = 1.0f/(1.0f + expf(val*SHARP));
            float sh = (0.2f + 0.8f*lam)*hw;
            int p = tile*PIX + pt;
            int x = p & 63, y = p >> 6;
            float o0 = 0.0f, o1 = 0.0f, o2 = 0.0f;
            if (maskq[pt]) {
                o0 = sh/(1.0f + expf(-(p0 + b_tex[0])));
                o1 = sh/(1.0f + expf(-(p1 + b_tex[1])));
                o2 = sh/(1.0f + expf(-(p2 + b_tex[2])));
            }
            out[((b*3 + 0)*IMG + y)*IMG + x] = o0;
            out[((b*3 + 1)*IMG + y)*IMG + x] = o1;
            out[((b*3 + 2)*IMG + y)*IMG + x] = o2;
        }
    }
}

extern "C" void kernel_launch(void* const* d_in, const int* in_sizes, int n_in,
                              void* d_out, int out_size, void* d_ws, size_t ws_size,
                              hipStream_t stream) {
    const float* latents   = (const float*)d_in[0];
    const float* phis      = (const float*)d_in[1];
    const float* thetas    = (const float*)d_in[2];
    const float* samples_u = (const float*)d_in[3];
    const float* w1        = (const float*)d_in[4];
    const float* b1        = (const float*)d_in[5];
    const float* w2        = (const float*)d_in[6];
    const float* b2        = (const float*)d_in[7];
    const float* w_sdf     = (const float*)d_in[8];
    const float* b_sdf     = (const float*)d_in[9];
    const float* w_tex     = (const float*)d_in[10];
    const float* b_tex     = (const float*)d_in[11];
    float* out = (float*)d_out;
    float* ws  = (float*)d_ws;

    setup_batch<<<dim3(BATCH), dim3(HID), 0, stream>>>(latents, phis, thetas, w1, b1, ws);
    setup_w2t<<<dim3(HID), dim3(HID), 0, stream>>>(w2, ws);
    render_kernel<<<dim3(BATCH*(IMG*IMG/PIX)), dim3(256), 0, stream>>>(
        samples_u, w1, w2, b2, w_sdf, b_sdf, w_tex, b_tex, ws, out);
}

// Round 5
// 268.376 us; speedup vs baseline: 1.2504x; 1.0082x over previous
//
#include <hip/hip_runtime.h>
#include <math.h>

typedef float vf2 __attribute__((ext_vector_type(2)));

#define BATCH 4
#define IMG 64
#define NSAMP 24
#define HID 128
#define LATN 128
#define PIX 8
#define MPT (PIX*NSAMP)   /* 192 points per block */
#define FOV_T 0.57735026918962576f
#define CAMD 2.0f
#define NEARP 1.0f
#define STEP (2.0f/24.0f)
#define SHARP 50.0f

/* workspace layout (floats) */
#define WS_LAT1 0                    /* B*128 */
#define WS_CAMR (BATCH*HID)         /* B*12 at 512 */
#define WS_W2T  1024                 /* 128*128 */
#define WS_L1P  (1024 + HID*HID)     /* B*128 float4: (w1x,w1y,w1z,lat1) */

__global__ void setup_batch(const float* __restrict__ latents,
                            const float* __restrict__ phis,
                            const float* __restrict__ thetas,
                            const float* __restrict__ w1,
                            const float* __restrict__ b1,
                            float* __restrict__ ws) {
    int b = blockIdx.x, j = threadIdx.x;
    float acc = b1[j];
    for (int k = 0; k < LATN; ++k)
        acc = fmaf(latents[b*LATN + k], w1[(3+k)*HID + j], acc);
    ws[WS_LAT1 + b*HID + j] = acc;
    /* packed layer-1 column for on-the-fly h1: (w1[0][j], w1[1][j], w1[2][j], lat) */
    float4 pk = make_float4(w1[j], w1[HID + j], w1[2*HID + j], acc);
    *(float4*)&ws[WS_L1P + (b*HID + j)*4] = pk;
    if (j == 0) {
        float ph = phis[b], th = thetas[b];
        float cp = cosf(ph), sp = sinf(ph), ct = cosf(th), st = sinf(th);
        float cx = CAMD*cp*st, cy = CAMD*sp, cz = CAMD*cp*ct;
        float nc = sqrtf(cx*cx + cy*cy + cz*cz);
        float fx = -cx/nc, fy = -cy/nc, fz = -cz/nc;
        float rx = fz, rz = -fx;
        float nr = sqrtf(rx*rx + rz*rz);
        rx /= nr; rz /= nr;
        float ux = fy*rz;
        float uy = fz*rx - fx*rz;
        float uz = -fy*rx;
        float* c = ws + WS_CAMR + b*12;
        c[0]=cx; c[1]=cy; c[2]=cz;
        c[3]=rx; c[4]=0.0f; c[5]=rz;
        c[6]=ux; c[7]=uy; c[8]=uz;
        c[9]=fx; c[10]=fy; c[11]=fz;
    }
}

__global__ void setup_w2t(const float* __restrict__ w2, float* __restrict__ ws) {
    int j = blockIdx.x, k = threadIdx.x;
    ws[WS_W2T + j*HID + k] = w2[k*HID + j];
}

__global__ __launch_bounds__(256)
void render_kernel(const float* __restrict__ samples_u,
                   const float* __restrict__ w1,
                   const float* __restrict__ w2,
                   const float* __restrict__ b2,
                   const float* __restrict__ w_sdf,
                   const float* __restrict__ b_sdf,
                   const float* __restrict__ w_tex,
                   const float* __restrict__ b_tex,
                   const float* __restrict__ ws,
                   float* __restrict__ out) {
    __shared__ __align__(16) float4 Ps4[MPT];   /* 3 KB */
    __shared__ float vals[MPT];
    __shared__ float vpart[4*MPT];              /* 3 KB */
    __shared__ float shadeH[4*HID];             /* 2 KB */
    __shared__ float shadeD[4*HID];             /* 2 KB */
    __shared__ float lat1s[HID];
    __shared__ float camR[12];
    __shared__ int   hitMs[PIX];
    __shared__ int   maskq[PIX];

    const int t    = threadIdx.x;
    const int lane = t & 63;
    const int wv   = __builtin_amdgcn_readfirstlane(t >> 6);  /* wave id 0..3 */
    const int blk  = blockIdx.x;
    const int b    = blk >> 9;
    const int tile = blk & 511;

    if (t < 12)  camR[t]  = ws[WS_CAMR + b*12 + t];
    if (t < HID) lat1s[t] = ws[WS_LAT1 + b*HID + t];
    if (t < PIX) {
        int p = tile*PIX + t;
        int x = p & 63, y = p >> 6;
        float xx = ((x + 0.5f)*(2.0f/IMG) - 1.0f)*FOV_T;
        float yy = ((y + 0.5f)*(2.0f/IMG) - 1.0f)*FOV_T;
        float n2 = xx*xx + yy*yy + 1.0f;
        maskq[t] = (4.0f - 3.0f*n2) >= 0.0f ? 1 : 0;
    }
    __syncthreads();

    /* fully-unmasked tile: write zeros, done */
    {
        int any = maskq[0]|maskq[1]|maskq[2]|maskq[3]|maskq[4]|maskq[5]|maskq[6]|maskq[7];
        if (!any) {
            if (t < PIX*3) {
                int q = t & 7, ch = t >> 3;
                int p = tile*PIX + q;
                int x = p & 63, y = p >> 6;
                out[((b*3 + ch)*IMG + y)*IMG + x] = 0.0f;
            }
            return;
        }
    }

    /* sample points for all 192 m */
    if (t < MPT) {
        int q = t / NSAMP, s = t - q*NSAMP;
        int p = tile*PIX + q;
        int x = p & 63, y = p >> 6;
        float xx =  ((x + 0.5f)*(2.0f/IMG) - 1.0f)*FOV_T;
        float yy = -(((y + 0.5f)*(2.0f/IMG) - 1.0f)*FOV_T);
        float inv = 1.0f/sqrtf(xx*xx + yy*yy + 1.0f);
        float d0 = xx*inv, d1 = yy*inv, d2 = -inv;
        float rxv = camR[3]*d0 + camR[6]*d1 - camR[9]*d2;
        float ryv = camR[4]*d0 + camR[7]*d1 - camR[10]*d2;
        float rzv = camR[5]*d0 + camR[8]*d1 - camR[11]*d2;
        float u  = samples_u[(y*IMG + x)*NSAMP + s];
        float tv = (s + u)*STEP + NEARP;
        Ps4[t] = make_float4(fmaf(rxv, tv, camR[0]),
                             fmaf(ryv, tv, camR[1]),
                             fmaf(rzv, tv, camR[2]), 0.0f);
    }
    __syncthreads();

    /* ---- march: h1 on the fly (scalar operands), packed-fp32 layer 2 ---- */
    {
        const float4* l1p = (const float4*)(ws + WS_L1P) + b*HID;   /* uniform */
        const vf2* b2v  = (const vf2*)b2    + wv*16;
        const vf2* wsdv = (const vf2*)w_sdf + wv*16;

        for (int g = 0; g < 3; ++g) {
            float4 P = Ps4[g*64 + lane];
            vf2 acc2[16];
            #pragma unroll
            for (int jj = 0; jj < 16; ++jj) acc2[jj] = 0.0f;
            #pragma unroll 2
            for (int k = 0; k < HID; ++k) {
                float4 wl = l1p[k];                           /* s_load_dwordx4 */
                float z = fmaf(P.x, wl.x, fmaf(P.y, wl.y, fmaf(P.z, wl.z, wl.w)));
                z = fmaxf(z, 0.0f);
                vf2 zz = z;
                const vf2* wr2 = (const vf2*)(w2 + k*HID) + wv*16;  /* uniform row slice */
                #pragma unroll
                for (int jj = 0; jj < 16; ++jj)
                    acc2[jj] = __builtin_elementwise_fma(zz, wr2[jj], acc2[jj]);
            }
            float val = 0.0f;
            #pragma unroll
            for (int jj = 0; jj < 16; ++jj) {
                vf2 r = acc2[jj] + b2v[jj];
                vf2 zero = 0.0f;
                r = __builtin_elementwise_max(r, zero);
                val = fmaf(r.x, wsdv[jj].x, fmaf(r.y, wsdv[jj].y, val));
            }
            vpart[wv*MPT + g*64 + lane] = val;
        }
    }
    __syncthreads();
    if (t < MPT)
        vals[t] = vpart[t] + vpart[MPT + t] + vpart[2*MPT + t]
                + vpart[3*MPT + t] + b_sdf[0];
    __syncthreads();

    /* hit selection */
    if (t < PIX) {
        int base = t*NSAMP;
        int idx = -1, bidx = 0;
        float bestv = 3.0e38f;
        for (int s = 0; s < NSAMP; ++s) {
            float v = vals[base + s];
            if (idx < 0 && v <= 0.0f) idx = s;
            if (v < bestv) { bestv = v; bidx = s; }
        }
        hitMs[t] = base + (idx >= 0 ? idx : bidx);
    }
    __syncthreads();

    /* ---- shading: one pixel per wave, 2 passes; wave-private LDS ---- */
    const float* w2t = ws + WS_W2T;
    const int j0 = lane, j1 = lane + 64;

    for (int pp = 0; pp < 2; ++pp) {
        int pt = pp*4 + wv;
        int hm = hitMs[pt];
        float4 H = Ps4[hm];
        float hx = H.x, hy = H.y, hz = H.z;

        float z0 = fmaf(hx, w1[j0], fmaf(hy, w1[HID+j0], fmaf(hz, w1[2*HID+j0], lat1s[j0])));
        float z1 = fmaf(hx, w1[j1], fmaf(hy, w1[HID+j1], fmaf(hz, w1[2*HID+j1], lat1s[j1])));
        float h10 = fmaxf(z0, 0.0f), h11 = fmaxf(z1, 0.0f);
        shadeH[wv*HID + j0] = h10;
        shadeH[wv*HID + j1] = h11;   /* intra-wave DS ordering suffices */

        /* forward h2 for j0,j1 with 4-way accumulators */
        float a00=0,a01=0,a02=0,a03=0, a10=0,a11=0,a12=0,a13=0;
        for (int k = 0; k < HID; k += 4) {
            float4 hv = *(const float4*)&shadeH[wv*HID + k];
            a00 = fmaf(hv.x, w2[(k+0)*HID + j0], a00);
            a10 = fmaf(hv.x, w2[(k+0)*HID + j1], a10);
            a01 = fmaf(hv.y, w2[(k+1)*HID + j0], a01);
            a11 = fmaf(hv.y, w2[(k+1)*HID + j1], a11);
            a02 = fmaf(hv.z, w2[(k+2)*HID + j0], a02);
            a12 = fmaf(hv.z, w2[(k+2)*HID + j1], a12);
            a03 = fmaf(hv.w, w2[(k+3)*HID + j0], a03);
            a13 = fmaf(hv.w, w2[(k+3)*HID + j1], a13);
        }
        float za = (a00+a01)+(a02+a03) + b2[j0];
        float zb = (a10+a11)+(a12+a13) + b2[j1];
        float h20 = fmaxf(za, 0.0f), h21 = fmaxf(zb, 0.0f);
        float wsd0 = w_sdf[j0], wsd1 = w_sdf[j1];
        shadeD[wv*HID + j0] = (za > 0.0f) ? wsd0 : 0.0f;
        shadeD[wv*HID + j1] = (zb > 0.0f) ? wsd1 : 0.0f;

        float pv = h20*wsd0 + h21*wsd1;
        float p0 = h20*w_tex[j0*3+0] + h21*w_tex[j1*3+0];
        float p1 = h20*w_tex[j0*3+1] + h21*w_tex[j1*3+1];
        float p2 = h20*w_tex[j0*3+2] + h21*w_tex[j1*3+2];
        #pragma unroll
        for (int off = 32; off > 0; off >>= 1) {
            pv += __shfl_xor(pv, off, 64);
            p0 += __shfl_xor(p0, off, 64);
            p1 += __shfl_xor(p1, off, 64);
            p2 += __shfl_xor(p2, off, 64);
        }

        /* backward: dh1 = w2t . dz2 */
        float d00=0,d01=0,d02=0,d03=0, d10=0,d11=0,d12=0,d13=0;
        for (int k = 0; k < HID; k += 4) {
            float4 dv = *(const float4*)&shadeD[wv*HID + k];
            d00 = fmaf(dv.x, w2t[(k+0)*HID + j0], d00);
            d10 = fmaf(dv.x, w2t[(k+0)*HID + j1], d10);
            d01 = fmaf(dv.y, w2t[(k+1)*HID + j0], d01);
            d11 = fmaf(dv.y, w2t[(k+1)*HID + j1], d11);
            d02 = fmaf(dv.z, w2t[(k+2)*HID + j0], d02);
            d12 = fmaf(dv.z, w2t[(k+2)*HID + j1], d12);
            d03 = fmaf(dv.w, w2t[(k+3)*HID + j0], d03);
            d13 = fmaf(dv.w, w2t[(k+3)*HID + j1], d13);
        }
        float dh0 = (d00+d01)+(d02+d03);
        float dh1v = (d10+d11)+(d12+d13);
        float dz10 = (h10 > 0.0f) ? dh0 : 0.0f;
        float dz11 = (h11 > 0.0f) ? dh1v : 0.0f;
        float g0 = w1[j0]*dz10 + w1[j1]*dz11;
        float g1 = w1[HID+j0]*dz10 + w1[HID+j1]*dz11;
        float g2 = w1[2*HID+j0]*dz10 + w1[2*HID+j1]*dz11;
        #pragma unroll
        for (int off = 32; off > 0; off >>= 1) {
            g0 += __shfl_xor(g0, off, 64);
            g1 += __shfl_xor(g1, off, 64);
            g2 += __shfl_xor(g2, off, 64);
        }

        if (lane == 0) {
            float val = pv + b_sdf[0];
            float nn = sqrtf(g0*g0 + g1*g1 + g2*g2) + 1e-8f;
            const float is3 = 0.57735026918962576f;
            float lam = (g0 + g1 + g2)*is3/nn;
            lam = fminf(fmaxf(lam, 0.0f), 1.0f);
            float hw = 1.0f/(1.0f + expf(val*SHARP));
            float sh = (0.2f + 0.8f*lam)*hw;
            int p = tile*PIX + pt;
            int x = p & 63, y = p >> 6;
            float o0 = 0.0f, o1 = 0.0f, o2 = 0.0f;
            if (maskq[pt]) {
                o0 = sh/(1.0f + expf(-(p0 + b_tex[0])));
                o1 = sh/(1.0f + expf(-(p1 + b_tex[1])));
                o2 = sh/(1.0f + expf(-(p2 + b_tex[2])));
            }
            out[((b*3 + 0)*IMG + y)*IMG + x] = o0;
            out[((b*3 + 1)*IMG + y)*IMG + x] = o1;
            out[((b*3 + 2)*IMG + y)*IMG + x] = o2;
        }
    }
}

extern "C" void kernel_launch(void* const* d_in, const int* in_sizes, int n_in,
                              void* d_out, int out_size, void* d_ws, size_t ws_size,
                              hipStream_t stream) {
    const float* latents   = (const float*)d_in[0];
    const float* phis      = (const float*)d_in[1];
    const float* thetas    = (const float*)d_in[2];
    const float* samples_u = (const float*)d_in[3];
    const float* w1        = (const float*)d_in[4];
    const float* b1        = (const float*)d_in[5];
    const float* w2        = (const float*)d_in[6];
    const float* b2        = (const float*)d_in[7];
    const float* w_sdf     = (const float*)d_in[8];
    const float* b_sdf     = (const float*)d_in[9];
    const float* w_tex     = (const float*)d_in[10];
    const float* b_tex     = (const float*)d_in[11];
    float* out = (float*)d_out;
    float* ws  = (float*)d_ws;

    setup_batch<<<dim3(BATCH), dim3(HID), 0, stream>>>(latents, phis, thetas, w1, b1, ws);
    setup_w2t<<<dim3(HID), dim3(HID), 0, stream>>>(w2, ws);
    render_kernel<<<dim3(BATCH*(IMG*IMG/PIX)), dim3(256), 0, stream>>>(
        samples_u, w1, w2, b2, w_sdf, b_sdf, w_tex, b_tex, ws, out);
}

// Round 6
// 254.855 us; speedup vs baseline: 1.3168x; 1.0531x over previous
//
#include <hip/hip_runtime.h>
#include <math.h>

typedef float vf2 __attribute__((ext_vector_type(2)));

#define BATCH 4
#define IMG 64
#define NSAMP 24
#define HID 128
#define LATN 128
#define PIX 8
#define MPT (PIX*NSAMP)   /* 192 points per block */
#define FOV_T 0.57735026918962576f
#define CAMD 2.0f
#define NEARP 1.0f
#define STEP (2.0f/24.0f)
#define SHARP 50.0f

/* workspace layout (floats) */
#define WS_LAT1 0                    /* B*128 */
#define WS_CAMR (BATCH*HID)         /* B*12 at 512 */
#define WS_W2T  1024                 /* 128*128 */
#define WS_L1P  (1024 + HID*HID)     /* B*128 float4: (w1x,w1y,w1z,lat1) */

__global__ void setup_batch(const float* __restrict__ latents,
                            const float* __restrict__ phis,
                            const float* __restrict__ thetas,
                            const float* __restrict__ w1,
                            const float* __restrict__ b1,
                            float* __restrict__ ws) {
    int b = blockIdx.x, j = threadIdx.x;
    float acc = b1[j];
    for (int k = 0; k < LATN; ++k)
        acc = fmaf(latents[b*LATN + k], w1[(3+k)*HID + j], acc);
    ws[WS_LAT1 + b*HID + j] = acc;
    /* packed layer-1 column for on-the-fly h1: (w1[0][j], w1[1][j], w1[2][j], lat) */
    float4 pk = make_float4(w1[j], w1[HID + j], w1[2*HID + j], acc);
    *(float4*)&ws[WS_L1P + (b*HID + j)*4] = pk;
    if (j == 0) {
        float ph = phis[b], th = thetas[b];
        float cp = cosf(ph), sp = sinf(ph), ct = cosf(th), st = sinf(th);
        float cx = CAMD*cp*st, cy = CAMD*sp, cz = CAMD*cp*ct;
        float nc = sqrtf(cx*cx + cy*cy + cz*cz);
        float fx = -cx/nc, fy = -cy/nc, fz = -cz/nc;
        float rx = fz, rz = -fx;
        float nr = sqrtf(rx*rx + rz*rz);
        rx /= nr; rz /= nr;
        float ux = fy*rz;
        float uy = fz*rx - fx*rz;
        float uz = -fy*rx;
        float* c = ws + WS_CAMR + b*12;
        c[0]=cx; c[1]=cy; c[2]=cz;
        c[3]=rx; c[4]=0.0f; c[5]=rz;
        c[6]=ux; c[7]=uy; c[8]=uz;
        c[9]=fx; c[10]=fy; c[11]=fz;
    }
}

__global__ void setup_w2t(const float* __restrict__ w2, float* __restrict__ ws) {
    int j = blockIdx.x, k = threadIdx.x;
    ws[WS_W2T + j*HID + k] = w2[k*HID + j];
}

__global__ __launch_bounds__(256, 4)
void render_kernel(const float* __restrict__ samples_u,
                   const float* __restrict__ w1,
                   const float* __restrict__ w2,
                   const float* __restrict__ b2,
                   const float* __restrict__ w_sdf,
                   const float* __restrict__ b_sdf,
                   const float* __restrict__ w_tex,
                   const float* __restrict__ b_tex,
                   const float* __restrict__ ws,
                   float* __restrict__ out) {
    __shared__ __align__(16) float4 Ps4[MPT];   /* 3 KB */
    __shared__ float vals[MPT];
    __shared__ float vpart[4*MPT];              /* 3 KB */
    __shared__ float shadeH[4*HID];             /* 2 KB */
    __shared__ float shadeD[4*HID];             /* 2 KB */
    __shared__ float lat1s[HID];
    __shared__ float camR[12];
    __shared__ int   hitMs[PIX];
    __shared__ int   maskq[PIX];

    const int t    = threadIdx.x;
    const int lane = t & 63;
    const int wv   = __builtin_amdgcn_readfirstlane(t >> 6);  /* wave id 0..3 */
    const int blk  = blockIdx.x;
    const int b    = blk >> 9;
    const int tile = blk & 511;

    if (t < 12)  camR[t]  = ws[WS_CAMR + b*12 + t];
    if (t < HID) lat1s[t] = ws[WS_LAT1 + b*HID + t];
    if (t < PIX) {
        int p = tile*PIX + t;
        int x = p & 63, y = p >> 6;
        float xx = ((x + 0.5f)*(2.0f/IMG) - 1.0f)*FOV_T;
        float yy = ((y + 0.5f)*(2.0f/IMG) - 1.0f)*FOV_T;
        float n2 = xx*xx + yy*yy + 1.0f;
        maskq[t] = (4.0f - 3.0f*n2) >= 0.0f ? 1 : 0;
    }
    __syncthreads();

    /* fully-unmasked tile: write zeros, done (uniform branch via readfirstlane) */
    {
        int any = maskq[0]|maskq[1]|maskq[2]|maskq[3]|maskq[4]|maskq[5]|maskq[6]|maskq[7];
        any = __builtin_amdgcn_readfirstlane(any);
        if (!any) {
            if (t < PIX*3) {
                int q = t & 7, ch = t >> 3;
                int p = tile*PIX + q;
                int x = p & 63, y = p >> 6;
                out[((b*3 + ch)*IMG + y)*IMG + x] = 0.0f;
            }
            return;
        }
    }

    /* sample points for all 192 m */
    if (t < MPT) {
        int q = t / NSAMP, s = t - q*NSAMP;
        int p = tile*PIX + q;
        int x = p & 63, y = p >> 6;
        float xx =  ((x + 0.5f)*(2.0f/IMG) - 1.0f)*FOV_T;
        float yy = -(((y + 0.5f)*(2.0f/IMG) - 1.0f)*FOV_T);
        float inv = 1.0f/sqrtf(xx*xx + yy*yy + 1.0f);
        float d0 = xx*inv, d1 = yy*inv, d2 = -inv;
        float rxv = camR[3]*d0 + camR[6]*d1 - camR[9]*d2;
        float ryv = camR[4]*d0 + camR[7]*d1 - camR[10]*d2;
        float rzv = camR[5]*d0 + camR[8]*d1 - camR[11]*d2;
        float u  = samples_u[(y*IMG + x)*NSAMP + s];
        float tv = (s + u)*STEP + NEARP;
        Ps4[t] = make_float4(fmaf(rxv, tv, camR[0]),
                             fmaf(ryv, tv, camR[1]),
                             fmaf(rzv, tv, camR[2]), 0.0f);
    }
    __syncthreads();

    /* ---- march: all 192 points in one k-loop; each w2 pair loaded once,
       used for 3 pk_fmas (3x fewer scalar loads than per-group loops) ---- */
    {
        const float4* l1p = (const float4*)(ws + WS_L1P) + b*HID;   /* uniform */
        const vf2* b2v  = (const vf2*)b2    + wv*16;
        const vf2* wsdv = (const vf2*)w_sdf + wv*16;

        float4 P0 = Ps4[lane];
        float4 P1 = Ps4[64 + lane];
        float4 P2 = Ps4[128 + lane];

        vf2 a0[16], a1[16], a2[16];
        #pragma unroll
        for (int jj = 0; jj < 16; ++jj) { a0[jj] = 0.0f; a1[jj] = 0.0f; a2[jj] = 0.0f; }

        #pragma unroll 2
        for (int k = 0; k < HID; ++k) {
            float4 wl = l1p[k];                                   /* s_load_dwordx4 */
            const vf2* wr2 = (const vf2*)(w2 + k*HID) + wv*16;    /* uniform slice */
            float z0 = fmaxf(fmaf(P0.x, wl.x, fmaf(P0.y, wl.y, fmaf(P0.z, wl.z, wl.w))), 0.0f);
            float z1 = fmaxf(fmaf(P1.x, wl.x, fmaf(P1.y, wl.y, fmaf(P1.z, wl.z, wl.w))), 0.0f);
            float z2 = fmaxf(fmaf(P2.x, wl.x, fmaf(P2.y, wl.y, fmaf(P2.z, wl.z, wl.w))), 0.0f);
            vf2 zz0 = z0, zz1 = z1, zz2 = z2;
            #pragma unroll
            for (int jj = 0; jj < 16; ++jj) {
                vf2 w = wr2[jj];
                a0[jj] = __builtin_elementwise_fma(zz0, w, a0[jj]);
                a1[jj] = __builtin_elementwise_fma(zz1, w, a1[jj]);
                a2[jj] = __builtin_elementwise_fma(zz2, w, a2[jj]);
            }
        }

        float v0 = 0.0f, v1 = 0.0f, v2 = 0.0f;
        #pragma unroll
        for (int jj = 0; jj < 16; ++jj) {
            vf2 bb = b2v[jj], wsd = wsdv[jj], zero = 0.0f;
            vf2 r0 = __builtin_elementwise_max(a0[jj] + bb, zero);
            vf2 r1 = __builtin_elementwise_max(a1[jj] + bb, zero);
            vf2 r2 = __builtin_elementwise_max(a2[jj] + bb, zero);
            v0 = fmaf(r0.x, wsd.x, fmaf(r0.y, wsd.y, v0));
            v1 = fmaf(r1.x, wsd.x, fmaf(r1.y, wsd.y, v1));
            v2 = fmaf(r2.x, wsd.x, fmaf(r2.y, wsd.y, v2));
        }
        vpart[wv*MPT +       lane] = v0;
        vpart[wv*MPT +  64 + lane] = v1;
        vpart[wv*MPT + 128 + lane] = v2;
    }
    __syncthreads();
    if (t < MPT)
        vals[t] = vpart[t] + vpart[MPT + t] + vpart[2*MPT + t]
                + vpart[3*MPT + t] + b_sdf[0];
    __syncthreads();

    /* hit selection */
    if (t < PIX) {
        int base = t*NSAMP;
        int idx = -1, bidx = 0;
        float bestv = 3.0e38f;
        for (int s = 0; s < NSAMP; ++s) {
            float v = vals[base + s];
            if (idx < 0 && v <= 0.0f) idx = s;
            if (v < bestv) { bestv = v; bidx = s; }
        }
        hitMs[t] = base + (idx >= 0 ? idx : bidx);
    }
    __syncthreads();

    /* ---- shading: one pixel per wave, 2 passes; wave-private LDS ---- */
    const float* w2t = ws + WS_W2T;
    const int j0 = lane, j1 = lane + 64;

    for (int pp = 0; pp < 2; ++pp) {
        int pt = pp*4 + wv;
        int hm = hitMs[pt];
        float4 H = Ps4[hm];
        float hx = H.x, hy = H.y, hz = H.z;

        float z0 = fmaf(hx, w1[j0], fmaf(hy, w1[HID+j0], fmaf(hz, w1[2*HID+j0], lat1s[j0])));
        float z1 = fmaf(hx, w1[j1], fmaf(hy, w1[HID+j1], fmaf(hz, w1[2*HID+j1], lat1s[j1])));
        float h10 = fmaxf(z0, 0.0f), h11 = fmaxf(z1, 0.0f);
        shadeH[wv*HID + j0] = h10;
        shadeH[wv*HID + j1] = h11;   /* intra-wave DS ordering suffices */

        /* forward h2 for j0,j1 with 4-way accumulators */
        float a00=0,a01=0,a02=0,a03=0, a10=0,a11=0,a12=0,a13=0;
        for (int k = 0; k < HID; k += 4) {
            float4 hv = *(const float4*)&shadeH[wv*HID + k];
            a00 = fmaf(hv.x, w2[(k+0)*HID + j0], a00);
            a10 = fmaf(hv.x, w2[(k+0)*HID + j1], a10);
            a01 = fmaf(hv.y, w2[(k+1)*HID + j0], a01);
            a11 = fmaf(hv.y, w2[(k+1)*HID + j1], a11);
            a02 = fmaf(hv.z, w2[(k+2)*HID + j0], a02);
            a12 = fmaf(hv.z, w2[(k+2)*HID + j1], a12);
            a03 = fmaf(hv.w, w2[(k+3)*HID + j0], a03);
            a13 = fmaf(hv.w, w2[(k+3)*HID + j1], a13);
        }
        float za = (a00+a01)+(a02+a03) + b2[j0];
        float zb = (a10+a11)+(a12+a13) + b2[j1];
        float h20 = fmaxf(za, 0.0f), h21 = fmaxf(zb, 0.0f);
        float wsd0 = w_sdf[j0], wsd1 = w_sdf[j1];
        shadeD[wv*HID + j0] = (za > 0.0f) ? wsd0 : 0.0f;
        shadeD[wv*HID + j1] = (zb > 0.0f) ? wsd1 : 0.0f;

        float pv = h20*wsd0 + h21*wsd1;
        float p0 = h20*w_tex[j0*3+0] + h21*w_tex[j1*3+0];
        float p1 = h20*w_tex[j0*3+1] + h21*w_tex[j1*3+1];
        float p2 = h20*w_tex[j0*3+2] + h21*w_tex[j1*3+2];
        #pragma unroll
        for (int off = 32; off > 0; off >>= 1) {
            pv += __shfl_xor(pv, off, 64);
            p0 += __shfl_xor(p0, off, 64);
            p1 += __shfl_xor(p1, off, 64);
            p2 += __shfl_xor(p2, off, 64);
        }

        /* backward: dh1 = w2t . dz2 */
        float d00=0,d01=0,d02=0,d03=0, d10=0,d11=0,d12=0,d13=0;
        for (int k = 0; k < HID; k += 4) {
            float4 dv = *(const float4*)&shadeD[wv*HID + k];
            d00 = fmaf(dv.x, w2t[(k+0)*HID + j0], d00);
            d10 = fmaf(dv.x, w2t[(k+0)*HID + j1], d10);
            d01 = fmaf(dv.y, w2t[(k+1)*HID + j0], d01);
            d11 = fmaf(dv.y, w2t[(k+1)*HID + j1], d11);
            d02 = fmaf(dv.z, w2t[(k+2)*HID + j0], d02);
            d12 = fmaf(dv.z, w2t[(k+2)*HID + j1], d12);
            d03 = fmaf(dv.w, w2t[(k+3)*HID + j0], d03);
            d13 = fmaf(dv.w, w2t[(k+3)*HID + j1], d13);
        }
        float dh0 = (d00+d01)+(d02+d03);
        float dh1v = (d10+d11)+(d12+d13);
        float dz10 = (h10 > 0.0f) ? dh0 : 0.0f;
        float dz11 = (h11 > 0.0f) ? dh1v : 0.0f;
        float g0 = w1[j0]*dz10 + w1[j1]*dz11;
        float g1 = w1[HID+j0]*dz10 + w1[HID+j1]*dz11;
        float g2 = w1[2*HID+j0]*dz10 + w1[2*HID+j1]*dz11;
        #pragma unroll
        for (int off = 32; off > 0; off >>= 1) {
            g0 += __shfl_xor(g0, off, 64);
            g1 += __shfl_xor(g1, off, 64);
            g2 += __shfl_xor(g2, off, 64);
        }

        if (lane == 0) {
            float val = pv + b_sdf[0];
            float nn = sqrtf(g0*g0 + g1*g1 + g2*g2) + 1e-8f;
            const float is3 = 0.57735026918962576f;
            float lam = (g0 + g1 + g2)*is3/nn;
            lam = fminf(fmaxf(lam, 0.0f), 1.0f);
            float hw = 1.0f/(1.0f + expf(val*SHARP));
            float sh = (0.2f + 0.8f*lam)*hw;
            int p = tile*PIX + pt;
            int x = p & 63, y = p >> 6;
            float o0 = 0.0f, o1 = 0.0f, o2 = 0.0f;
            if (maskq[pt]) {
                o0 = sh/(1.0f + expf(-(p0 + b_tex[0])));
                o1 = sh/(1.0f + expf(-(p1 + b_tex[1])));
                o2 = sh/(1.0f + expf(-(p2 + b_tex[2])));
            }
            out[((b*3 + 0)*IMG + y)*IMG + x] = o0;
            out[((b*3 + 1)*IMG + y)*IMG + x] = o1;
            out[((b*3 + 2)*IMG + y)*IMG + x] = o2;
        }
    }
}

extern "C" void kernel_launch(void* const* d_in, const int* in_sizes, int n_in,
                              void* d_out, int out_size, void* d_ws, size_t ws_size,
                              hipStream_t stream) {
    const float* latents   = (const float*)d_in[0];
    const float* phis      = (const float*)d_in[1];
    const float* thetas    = (const float*)d_in[2];
    const float* samples_u = (const float*)d_in[3];
    const float* w1        = (const float*)d_in[4];
    const float* b1        = (const float*)d_in[5];
    const float* w2        = (const float*)d_in[6];
    const float* b2        = (const float*)d_in[7];
    const float* w_sdf     = (const float*)d_in[8];
    const float* b_sdf     = (const float*)d_in[9];
    const float* w_tex     = (const float*)d_in[10];
    const float* b_tex     = (const float*)d_in[11];
    float* out = (float*)d_out;
    float* ws  = (float*)d_ws;

    setup_batch<<<dim3(BATCH), dim3(HID), 0, stream>>>(latents, phis, thetas, w1, b1, ws);
    setup_w2t<<<dim3(HID), dim3(HID), 0, stream>>>(w2, ws);
    render_kernel<<<dim3(BATCH*(IMG*IMG/PIX)), dim3(256), 0, stream>>>(
        samples_u, w1, w2, b2, w_sdf, b_sdf, w_tex, b_tex, ws, out);
}